// Round 7
// baseline (197.016 us; speedup 1.0000x reference)
//
#include <hip/hip_runtime.h>

namespace {
constexpr int CC = 3, FF = 51;
constexpr int HOUT = 384, WOUT = 384;
constexpr int HIN = 434, WIN = 434;
constexpr int KY = 8;                 // vertical outputs per thread (amortize LDS)
constexpr int LANES = 64;             // x-pixels per block
constexpr int NW = 4;                 // fx-split waves per block (13/13/13/12 taps)
constexpr int EXT = LANES + FF - 1;   // 114 valid f16 per channel strip
constexpr int LPAD = 128;             // strip pitch (f16), pow2 -> static indices
constexpr int NSTEP = FF + KY - 1;    // 58 input rows per tile
constexpr int NSG = CC * LPAD / LANES;   // 6 staged elems/lane (exact)
constexpr int NQW = 4;                // b64 LDS reads per (c, step)
constexpr int NPW = 8;                // f16 pairs per (t, step)
constexpr int SSTRIDE = NW * CC * LPAD;  // u16 elems per LDS buffer (1536)

using half2v = _Float16 __attribute__((ext_vector_type(2)));

// r4/r6-proven path: __builtin_amdgcn_fdot2 emits v_dot2_f32_f16.
// (r5 lesson: hand-written VOP3P inline asm broke numerics — keep the builtin.)
__device__ __forceinline__ float fdot2f(half2v a, half2v b, float c) {
#if __has_builtin(__builtin_amdgcn_fdot2)
  return __builtin_amdgcn_fdot2(a, b, c, false);
#else
  return c + (float)a.x * (float)b.x + (float)a.y * (float)b.y;
#endif
}
}  // namespace

__global__ __launch_bounds__(NW* LANES, 2) void sepconv_kernel(
    const float* __restrict__ In, const float* __restrict__ Ver,
    const float* __restrict__ Hor, float* __restrict__ Out) {
  const int lane = threadIdx.x;
  const int w = threadIdx.y;          // fx-quarter
  const int x0 = blockIdx.x * LANES;
  const int y0 = blockIdx.y * KY;
  const int b = blockIdx.z;
  const int x = x0 + lane;
  const int fxBase = 13 * w;          // taps [fxBase, fxBase+ntaps)
  const int ntaps = (w < 3) ? 13 : 12;
  const int aw = (lane + fxBase) & 3;        // alignment class
  const int bw = lane + fxBase - aw;         // 4-f16-aligned strip base elem

  __shared__ __align__(16) unsigned short sIn[2][NW][CC][LPAD];
  __shared__ float sRed[NW - 1][CC][KY][LANES];
  unsigned short* const sflat = &sIn[0][0][0][0];

  const size_t HW = (size_t)HOUT * WOUT;

  // ---- per-pixel horizontal taps for this wave's fx range (OOB -> 0)
  half2v hp[KY][NPW];
  {
    const float* horx = Hor + (size_t)b * FF * HW + x;
#pragma unroll
    for (int t = 0; t < KY; ++t) {
      const float* hb = horx + (size_t)(y0 + t) * WOUT;
#pragma unroll
      for (int j = 0; j < NPW; ++j) {
        const int u0 = 2 * j - aw;
        const int u1 = u0 + 1;
        float f0 = (u0 >= 0 && u0 < ntaps) ? hb[(size_t)(fxBase + u0) * HW] : 0.0f;
        float f1 = (u1 >= 0 && u1 < ntaps) ? hb[(size_t)(fxBase + u1) * HW] : 0.0f;
        half2v p;
        p.x = (_Float16)f0;  // RTE
        p.y = (_Float16)f1;
        hp[t][j] = p;
      }
    }
  }

  const float* inb = In + ((size_t)b * CC * HIN + y0) * WIN + x0;
  const float* verb = Ver + (size_t)b * FF * HW + (size_t)y0 * WOUT + x;

  float acc[CC][KY] = {};
  float sv[NSG];

  // Staging geometry (indices compile-time per k):
  //   k: c = k>>1, e = lane + (k&1)*64. Odd-k lanes with e >= EXT store 0.0
  //   into the pad region so b64 over-reads (up to elem 115) see zeros.
  //   x0 + EXT - 1 = 433 < WIN=434 -> no x guard needed.
#define STAGE_LOAD(R)                                                         \
  _Pragma("unroll") for (int k = 0; k < NSG; ++k) {                           \
    const int e = lane + (k & 1) * 64;                                        \
    const bool valid = ((k & 1) == 0) || (lane < EXT - LANES);                \
    sv[k] = valid ? inb[(size_t)((k >> 1) * HIN + (R)) * WIN + e] : 0.0f;     \
  }

#define STAGE_WRITE(BF)                                                       \
  _Pragma("unroll") for (int k = 0; k < NSG; ++k) {                           \
    const int e = lane + (k & 1) * 64;                                        \
    sflat[(BF)*SSTRIDE + (w * CC + (k >> 1)) * LPAD + e] =                    \
        __builtin_bit_cast(unsigned short, (_Float16)sv[k]);                  \
  }

#define COMPUTE(R, BF)                                                        \
  {                                                                           \
    float vv[KY];                                                             \
    _Pragma("unroll") for (int t = 0; t < KY; ++t) {                          \
      const int u = (R)-t;                                                    \
      vv[t] = (u >= 0 && u < FF)                                              \
                  ? verb[(size_t)u * HW + (size_t)t * WOUT]                   \
                  : 0.0f;                                                     \
    }                                                                         \
    _Pragma("unroll") for (int c = 0; c < CC; ++c) {                          \
      const unsigned short* rp = sflat + (BF)*SSTRIDE + (w * CC + c) * LPAD + bw; \
      float d[KY] = {};                                                       \
      _Pragma("unroll") for (int q = 0; q < NQW; ++q) {                       \
        const uint2 u2 = *reinterpret_cast<const uint2*>(rp + 4 * q);         \
        const half2v p0 = __builtin_bit_cast(half2v, u2.x);                   \
        const half2v p1 = __builtin_bit_cast(half2v, u2.y);                   \
        _Pragma("unroll") for (int t = 0; t < KY; ++t) {                      \
          d[t] = fdot2f(p0, hp[t][2 * q], d[t]);                              \
          d[t] = fdot2f(p1, hp[t][2 * q + 1], d[t]);                          \
        }                                                                     \
      }                                                                       \
      _Pragma("unroll") for (int t = 0; t < KY; ++t) acc[c][t] += d[t] * vv[t];\
    }                                                                         \
  }

  // ---- prologue: stage input row y0 into buffer 0 (wave-private, no barriers)
  STAGE_LOAD(0);
  STAGE_WRITE(0);

  // ---- main loop, 2x unrolled, constant buffer indices, barrier-free
#pragma unroll 1
  for (int r = 0; r < NSTEP; r += 2) {
    STAGE_LOAD(r + 1);  // issue early (T14); consumed after COMPUTE(r)
    COMPUTE(r, 0);
    STAGE_WRITE(1);
    const bool more = (r + 2 < NSTEP);
    if (more) { STAGE_LOAD(r + 2); }
    COMPUTE(r + 1, 1);
    if (more) { STAGE_WRITE(0); }
  }

  // ---- cross-wave fx reduction (4-way), then store
  if (w > 0) {
#pragma unroll
    for (int c = 0; c < CC; ++c)
#pragma unroll
      for (int t = 0; t < KY; ++t) sRed[w - 1][c][t][lane] = acc[c][t];
  }
  __syncthreads();
  if (w == 0) {
    float* outb = Out + (size_t)b * CC * HW + (size_t)y0 * WOUT + x0 + lane;
#pragma unroll
    for (int c = 0; c < CC; ++c)
#pragma unroll
      for (int t = 0; t < KY; ++t)
        outb[(size_t)c * HW + (size_t)t * WOUT] =
            acc[c][t] + sRed[0][c][t][lane] + sRed[1][c][t][lane] +
            sRed[2][c][t][lane];
  }
#undef STAGE_LOAD
#undef STAGE_WRITE
#undef COMPUTE
}

extern "C" void kernel_launch(void* const* d_in, const int* in_sizes, int n_in,
                              void* d_out, int out_size, void* d_ws, size_t ws_size,
                              hipStream_t stream) {
  const float* In = (const float*)d_in[0];
  const float* Ver = (const float*)d_in[1];
  const float* Hor = (const float*)d_in[2];
  float* Out = (float*)d_out;

  dim3 grid(WOUT / LANES, HOUT / KY, 4);
  dim3 block(LANES, NW, 1);
  sepconv_kernel<<<grid, block, 0, stream>>>(In, Ver, Hor, Out);
}

// Round 8
// 162.157 us; speedup vs baseline: 1.2150x; 1.2150x over previous
//
#include <hip/hip_runtime.h>

namespace {
constexpr int CC = 3, FF = 51;
constexpr int BB = 4;
constexpr int HOUT = 384, WOUT = 384;
constexpr int HIN = 434, WIN = 434;
constexpr int KY = 4;                 // vertical outputs per thread (r6-proven)
constexpr int LANES = 64;             // x-pixels per block
constexpr int NW = 4;                 // fx-split waves per block (13/13/13/12 taps)
constexpr int EXT = LANES + FF - 1;   // 114 valid f16 per channel strip
constexpr int LPAD = 128;             // strip pitch (f16): 64 lanes x 2 f16 = one DMA
constexpr int NSTEP = FF + KY - 1;    // 54 input rows per tile (even)
constexpr int NSG = CC * LPAD / LANES;   // 6 staged elems/lane (fallback path)
constexpr int NQW = 4;                // b64 LDS reads per (c, step)
constexpr int NPW = 8;                // f16 pairs per (t, step)
constexpr int SSTRIDE = NW * CC * LPAD;  // u16 elems per LDS buffer (1536)
constexpr size_t IN16_BYTES = (size_t)BB * CC * HIN * WIN * 2;  // 4.52 MB

using half2v = _Float16 __attribute__((ext_vector_type(2)));

// r4/r6-proven path: __builtin_amdgcn_fdot2 emits v_dot2_f32_f16.
// (r5 lesson: hand-written VOP3P inline asm broke numerics — keep the builtin.)
__device__ __forceinline__ float fdot2f(half2v a, half2v b, float c) {
#if __has_builtin(__builtin_amdgcn_fdot2)
  return __builtin_amdgcn_fdot2(a, b, c, false);
#else
  return c + (float)a.x * (float)b.x + (float)a.y * (float)b.y;
#endif
}

#define GLLDS(G, L)                                                  \
  __builtin_amdgcn_global_load_lds(                                  \
      (const __attribute__((address_space(1))) void*)(G),            \
      (__attribute__((address_space(3))) void*)(L), 4, 0, 0)
}  // namespace

// ---- pre-kernel: In f32 -> f16 (RTE), packed pairs, into d_ws ----
__global__ void cvt16_kernel(const float* __restrict__ in,
                             unsigned int* __restrict__ out, int n2) {
  int i = blockIdx.x * blockDim.x + threadIdx.x;
  const int stride = gridDim.x * blockDim.x;
  for (; i < n2; i += stride) {
    const float2 v = *reinterpret_cast<const float2*>(in + 2 * (size_t)i);
    const unsigned short lo = __builtin_bit_cast(unsigned short, (_Float16)v.x);
    const unsigned short hi = __builtin_bit_cast(unsigned short, (_Float16)v.y);
    out[i] = ((unsigned int)hi << 16) | lo;
  }
}

template <bool DMA>
__global__ __launch_bounds__(NW* LANES, 2) void sepconv_kernel(
    const float* __restrict__ In, const float* __restrict__ Ver,
    const float* __restrict__ Hor, float* __restrict__ Out,
    const unsigned short* __restrict__ In16) {
  const int lane = threadIdx.x;
  const int w = threadIdx.y;          // fx-quarter
  const int x0 = blockIdx.x * LANES;
  const int y0 = blockIdx.y * KY;
  const int b = blockIdx.z;
  const int x = x0 + lane;
  const int fxBase = 13 * w;          // taps [fxBase, fxBase+ntaps)
  const int ntaps = (w < 3) ? 13 : 12;
  const int aw = (lane + fxBase) & 3;        // alignment class
  const int bw = lane + fxBase - aw;         // 4-f16-aligned strip base elem

  __shared__ __align__(16) unsigned short sIn[2][NW][CC][LPAD];
  __shared__ float sRed[NW - 1][CC][KY][LANES];
  unsigned short* const sflat = &sIn[0][0][0][0];

  const size_t HW = (size_t)HOUT * WOUT;

  // ---- per-pixel horizontal taps for this wave's fx range (OOB -> 0)
  half2v hp[KY][NPW];
  {
    const float* horx = Hor + (size_t)b * FF * HW + x;
#pragma unroll
    for (int t = 0; t < KY; ++t) {
      const float* hb = horx + (size_t)(y0 + t) * WOUT;
#pragma unroll
      for (int j = 0; j < NPW; ++j) {
        const int u0 = 2 * j - aw;
        const int u1 = u0 + 1;
        float f0 = (u0 >= 0 && u0 < ntaps) ? hb[(size_t)(fxBase + u0) * HW] : 0.0f;
        float f1 = (u1 >= 0 && u1 < ntaps) ? hb[(size_t)(fxBase + u1) * HW] : 0.0f;
        half2v p;
        p.x = (_Float16)f0;  // RTE
        p.y = (_Float16)f1;
        hp[t][j] = p;
      }
    }
  }

  const float* inb = In + ((size_t)b * CC * HIN + y0) * WIN + x0;
  const float* verb = Ver + (size_t)b * FF * HW + (size_t)y0 * WOUT + x;
  // f16 input base for this block (elems); row (c,R) = in16b + (c*HIN+R)*WIN
  const unsigned short* in16b =
      In16 + ((size_t)b * CC * HIN + y0) * WIN + x0;
  // per-lane DMA source byte offset, clamped so reads stay inside the row.
  // lane L writes LDS elems 2L,2L+1 (pad region e>=114 may get duplicated
  // finite values at the last x-block; those taps have hp==0).
  const int vmax = 2 * WIN - 4 - 2 * x0;  // >= 224 for all x0
  const int voff = (4 * lane < vmax) ? 4 * lane : vmax;

  float acc[CC][KY] = {};
  float sv[NSG];

  // ---- fallback staging (r6-proven): regs + cvt + ds_write ----
#define STAGE_LOAD(R)                                                         \
  _Pragma("unroll") for (int k = 0; k < NSG; ++k) {                           \
    const int e = lane + (k & 1) * 64;                                        \
    const bool valid = ((k & 1) == 0) || (lane < EXT - LANES);                \
    sv[k] = valid ? inb[(size_t)((k >> 1) * HIN + (R)) * WIN + e] : 0.0f;     \
  }

#define STAGE_WRITE(BF)                                                       \
  _Pragma("unroll") for (int k = 0; k < NSG; ++k) {                           \
    const int e = lane + (k & 1) * 64;                                        \
    sflat[(BF)*SSTRIDE + (w * CC + (k >> 1)) * LPAD + e] =                    \
        __builtin_bit_cast(unsigned short, (_Float16)sv[k]);                  \
  }

  // ---- DMA staging: one 4B/lane global_load_lds per channel, zero VALU ----
#define STAGE_DMA(R, BF)                                                      \
  _Pragma("unroll") for (int c = 0; c < CC; ++c) {                            \
    const unsigned short* g = in16b + (size_t)(c * HIN + (R)) * WIN;          \
    GLLDS((const char*)g + voff, &sIn[BF][w][c][0]);                          \
  }

#define COMPUTE(R, BF)                                                        \
  {                                                                           \
    float vv[KY];                                                             \
    _Pragma("unroll") for (int t = 0; t < KY; ++t) {                          \
      const int u = (R)-t;                                                    \
      vv[t] = (u >= 0 && u < FF)                                              \
                  ? verb[(size_t)u * HW + (size_t)t * WOUT]                   \
                  : 0.0f;                                                     \
    }                                                                         \
    _Pragma("unroll") for (int c = 0; c < CC; ++c) {                          \
      const unsigned short* rp = sflat + (BF)*SSTRIDE + (w * CC + c) * LPAD + bw; \
      float d[KY] = {};                                                       \
      _Pragma("unroll") for (int q = 0; q < NQW; ++q) {                       \
        const uint2 u2 = *reinterpret_cast<const uint2*>(rp + 4 * q);         \
        const half2v p0 = __builtin_bit_cast(half2v, u2.x);                   \
        const half2v p1 = __builtin_bit_cast(half2v, u2.y);                   \
        _Pragma("unroll") for (int t = 0; t < KY; ++t) {                      \
          d[t] = fdot2f(p0, hp[t][2 * q], d[t]);                              \
          d[t] = fdot2f(p1, hp[t][2 * q + 1], d[t]);                          \
        }                                                                     \
      }                                                                       \
      _Pragma("unroll") for (int t = 0; t < KY; ++t) acc[c][t] += d[t] * vv[t];\
    }                                                                         \
  }

  if constexpr (DMA) {
    STAGE_DMA(0, 0);  // prologue: row y0 -> buf 0
#pragma unroll 2
    for (int r = 0; r < NSTEP; ++r) {
      const int rn = (r + 1 < NSTEP) ? r + 1 : NSTEP - 1;  // clamped prefetch
      STAGE_DMA(rn, (r + 1) & 1);
      COMPUTE(r, r & 1);
    }
  } else {
    STAGE_LOAD(0);
    STAGE_WRITE(0);
#pragma unroll 1
    for (int r = 0; r < NSTEP; r += 2) {
      STAGE_LOAD(r + 1);
      COMPUTE(r, 0);
      STAGE_WRITE(1);
      const bool more = (r + 2 < NSTEP);
      if (more) { STAGE_LOAD(r + 2); }
      COMPUTE(r + 1, 1);
      if (more) { STAGE_WRITE(0); }
    }
  }

  // ---- cross-wave fx reduction (4-way), then store
  if (w > 0) {
#pragma unroll
    for (int c = 0; c < CC; ++c)
#pragma unroll
      for (int t = 0; t < KY; ++t) sRed[w - 1][c][t][lane] = acc[c][t];
  }
  __syncthreads();
  if (w == 0) {
    float* outb = Out + (size_t)b * CC * HW + (size_t)y0 * WOUT + x0 + lane;
#pragma unroll
    for (int c = 0; c < CC; ++c)
#pragma unroll
      for (int t = 0; t < KY; ++t)
        outb[(size_t)c * HW + (size_t)t * WOUT] =
            acc[c][t] + sRed[0][c][t][lane] + sRed[1][c][t][lane] +
            sRed[2][c][t][lane];
  }
#undef STAGE_LOAD
#undef STAGE_WRITE
#undef STAGE_DMA
#undef COMPUTE
}

extern "C" void kernel_launch(void* const* d_in, const int* in_sizes, int n_in,
                              void* d_out, int out_size, void* d_ws, size_t ws_size,
                              hipStream_t stream) {
  const float* In = (const float*)d_in[0];
  const float* Ver = (const float*)d_in[1];
  const float* Hor = (const float*)d_in[2];
  float* Out = (float*)d_out;

  dim3 grid(WOUT / LANES, HOUT / KY, BB);
  dim3 block(LANES, NW, 1);

  if (ws_size >= IN16_BYTES && d_ws != nullptr) {
    const int n2 = (int)(BB * CC * HIN * WIN / 2);  // exact (even count)
    cvt16_kernel<<<2048, 256, 0, stream>>>(In, (unsigned int*)d_ws, n2);
    sepconv_kernel<true><<<grid, block, 0, stream>>>(
        In, Ver, Hor, Out, (const unsigned short*)d_ws);
  } else {
    sepconv_kernel<false><<<grid, block, 0, stream>>>(In, Ver, Hor, Out,
                                                      nullptr);
  }
}

// Round 10
// 160.543 us; speedup vs baseline: 1.2272x; 1.0101x over previous
//
#include <hip/hip_runtime.h>

namespace {
constexpr int CC = 3, FF = 51;
constexpr int BB = 4;
constexpr int HOUT = 384, WOUT = 384;
constexpr int HIN = 434, WIN = 434;
constexpr int KY = 4;                 // vertical outputs per thread
constexpr int LANES = 64;             // x-pixels per block
constexpr int NW = 4;                 // fx-split waves per block (13/13/13/12 taps)
constexpr int EXT = LANES + FF - 1;   // 114 valid f16 per channel strip
constexpr int LPAD = 128;             // strip pitch (f16): 64 lanes x 2 f16 = one DMA
constexpr int NSTEP = FF + KY - 1;    // 54 input rows per tile
constexpr int NSG = CC * LPAD / LANES;   // 6 staged elems/lane (fallback path)
constexpr int NQW = 4;                // b64 LDS reads per (c, step)
constexpr int NPW = 8;                // f16 pairs per (t, step)
constexpr int SSTRIDE = NW * CC * LPAD;  // u16 elems per LDS buffer (1536)
constexpr size_t IN16_BYTES = (size_t)BB * CC * HIN * WIN * 2;  // 4.52 MB

using half2v = _Float16 __attribute__((ext_vector_type(2)));

// r4/r6-proven path: __builtin_amdgcn_fdot2 emits v_dot2_f32_f16.
// (r5 lesson: hand-written VOP3P inline asm broke numerics — keep the builtin.)
__device__ __forceinline__ float fdot2f(half2v a, half2v b, float c) {
#if __has_builtin(__builtin_amdgcn_fdot2)
  return __builtin_amdgcn_fdot2(a, b, c, false);
#else
  return c + (float)a.x * (float)b.x + (float)a.y * (float)b.y;
#endif
}

#define GLLDS(G, L)                                                  \
  __builtin_amdgcn_global_load_lds(                                  \
      (const __attribute__((address_space(1))) void*)(G),            \
      (__attribute__((address_space(3))) void*)(L), 4, 0, 0)

// WAR-race fence: all issued ds_reads must have sampled LDS before a
// later global_load_lds may overwrite that buffer (DMA write path is
// decoupled from the DS queue). sched_barrier pins compiler ordering.
#define LDS_FENCE()                                                  \
  asm volatile("s_waitcnt lgkmcnt(0)" ::: "memory");                 \
  __builtin_amdgcn_sched_barrier(0)
}  // namespace

// ---- pre-kernel: In f32 -> f16 (RTE), packed pairs, into d_ws ----
__global__ void cvt16_kernel(const float* __restrict__ in,
                             unsigned int* __restrict__ out, int n2) {
  int i = blockIdx.x * blockDim.x + threadIdx.x;
  const int stride = gridDim.x * blockDim.x;
  for (; i < n2; i += stride) {
    const float2 v = *reinterpret_cast<const float2*>(in + 2 * (size_t)i);
    const unsigned short lo = __builtin_bit_cast(unsigned short, (_Float16)v.x);
    const unsigned short hi = __builtin_bit_cast(unsigned short, (_Float16)v.y);
    out[i] = ((unsigned int)hi << 16) | lo;
  }
}

template <bool DMA>
__global__ __launch_bounds__(NW* LANES, 2) void sepconv_kernel(
    const float* __restrict__ In, const float* __restrict__ Ver,
    const float* __restrict__ Hor, float* __restrict__ Out,
    const unsigned short* __restrict__ In16) {
  const int lane = threadIdx.x;
  const int w = threadIdx.y;          // fx-quarter
  const int x0 = blockIdx.x * LANES;
  const int y0 = blockIdx.y * KY;
  const int b = blockIdx.z;
  const int x = x0 + lane;
  const int fxBase = 13 * w;          // taps [fxBase, fxBase+ntaps)
  const int ntaps = (w < 3) ? 13 : 12;
  const int aw = (lane + fxBase) & 3;        // alignment class
  const int bw = lane + fxBase - aw;         // 4-f16-aligned strip base elem

  __shared__ __align__(16) unsigned short sIn[2][NW][CC][LPAD];
  __shared__ float sRed[NW - 1][CC][KY][LANES];
  unsigned short* const sflat = &sIn[0][0][0][0];

  const size_t HW = (size_t)HOUT * WOUT;

  // ---- per-pixel horizontal taps for this wave's fx range (OOB -> 0)
  half2v hp[KY][NPW];
  {
    const float* horx = Hor + (size_t)b * FF * HW + x;
#pragma unroll
    for (int t = 0; t < KY; ++t) {
      const float* hb = horx + (size_t)(y0 + t) * WOUT;
#pragma unroll
      for (int j = 0; j < NPW; ++j) {
        const int u0 = 2 * j - aw;
        const int u1 = u0 + 1;
        float f0 = (u0 >= 0 && u0 < ntaps) ? hb[(size_t)(fxBase + u0) * HW] : 0.0f;
        float f1 = (u1 >= 0 && u1 < ntaps) ? hb[(size_t)(fxBase + u1) * HW] : 0.0f;
        half2v p;
        p.x = (_Float16)f0;  // RTE
        p.y = (_Float16)f1;
        hp[t][j] = p;
      }
    }
  }

  const float* inb = In + ((size_t)b * CC * HIN + y0) * WIN + x0;
  // guarded-path Ver base (per-lane)
  const float* verb = Ver + (size_t)b * FF * HW + (size_t)y0 * WOUT + x;
  // steady-path Ver bases: UNIFORM (no lane) -> SGPR base + lane voffset loads
  const float* vbase0 = Ver + (size_t)b * FF * HW + (size_t)(y0 + 0) * WOUT + x0;
  const float* vbase1 = Ver + (size_t)b * FF * HW + (size_t)(y0 + 1) * WOUT + x0;
  const float* vbase2 = Ver + (size_t)b * FF * HW + (size_t)(y0 + 2) * WOUT + x0;
  const float* vbase3 = Ver + (size_t)b * FF * HW + (size_t)(y0 + 3) * WOUT + x0;

  // f16 input base for this block (elems); row (c,R) = in16b + (c*HIN+R)*WIN
  const unsigned short* in16b =
      In16 + ((size_t)b * CC * HIN + y0) * WIN + x0;
  // per-lane DMA source byte offset, clamped so reads stay inside the row.
  const int vmax = 2 * WIN - 4 - 2 * x0;  // >= 224 for all x0
  const int voff = (4 * lane < vmax) ? 4 * lane : vmax;

  float acc[CC][KY] = {};
  float sv[NSG];

  // ---- fallback staging (r6-proven): regs + cvt + ds_write ----
#define STAGE_LOAD(R)                                                         \
  _Pragma("unroll") for (int k = 0; k < NSG; ++k) {                           \
    const int e = lane + (k & 1) * 64;                                        \
    const bool valid = ((k & 1) == 0) || (lane < EXT - LANES);                \
    sv[k] = valid ? inb[(size_t)((k >> 1) * HIN + (R)) * WIN + e] : 0.0f;     \
  }

#define STAGE_WRITE(BF)                                                       \
  _Pragma("unroll") for (int k = 0; k < NSG; ++k) {                           \
    const int e = lane + (k & 1) * 64;                                        \
    sflat[(BF)*SSTRIDE + (w * CC + (k >> 1)) * LPAD + e] =                    \
        __builtin_bit_cast(unsigned short, (_Float16)sv[k]);                  \
  }

  // ---- DMA staging: one 4B/lane global_load_lds per channel, zero VALU ----
#define STAGE_DMA(R, BF)                                                      \
  _Pragma("unroll") for (int c = 0; c < CC; ++c) {                            \
    const unsigned short* g = in16b + (size_t)(c * HIN + (R)) * WIN;          \
    GLLDS((const char*)g + voff, &sIn[BF][w][c][0]);                          \
  }

  // shared dot-product core: d[t] seeded by literal 0 in the first dot2
#define DOT_CORE(BF)                                                          \
    _Pragma("unroll") for (int c = 0; c < CC; ++c) {                          \
      const unsigned short* rp = sflat + (BF)*SSTRIDE + (w * CC + c) * LPAD + bw; \
      float d[KY];                                                            \
      {                                                                       \
        const uint2 u2 = *reinterpret_cast<const uint2*>(rp);                 \
        const half2v p0 = __builtin_bit_cast(half2v, u2.x);                   \
        const half2v p1 = __builtin_bit_cast(half2v, u2.y);                   \
        _Pragma("unroll") for (int t = 0; t < KY; ++t) {                      \
          d[t] = fdot2f(p0, hp[t][0], 0.0f);                                  \
          d[t] = fdot2f(p1, hp[t][1], d[t]);                                  \
        }                                                                     \
      }                                                                       \
      _Pragma("unroll") for (int q = 1; q < NQW; ++q) {                       \
        const uint2 u2 = *reinterpret_cast<const uint2*>(rp + 4 * q);         \
        const half2v p0 = __builtin_bit_cast(half2v, u2.x);                   \
        const half2v p1 = __builtin_bit_cast(half2v, u2.y);                   \
        _Pragma("unroll") for (int t = 0; t < KY; ++t) {                      \
          d[t] = fdot2f(p0, hp[t][2 * q], d[t]);                              \
          d[t] = fdot2f(p1, hp[t][2 * q + 1], d[t]);                          \
        }                                                                     \
      }                                                                       \
      _Pragma("unroll") for (int t = 0; t < KY; ++t)                          \
        acc[c][t] = __builtin_fmaf(d[t], vv[t], acc[c][t]);                   \
    }

  // guarded compute (prologue/epilogue/fallback)
#define COMPUTE_G(R, BF)                                                      \
  {                                                                           \
    float vv[KY];                                                             \
    _Pragma("unroll") for (int t = 0; t < KY; ++t) {                          \
      const int u = (R)-t;                                                    \
      vv[t] = (u >= 0 && u < FF)                                              \
                  ? verb[(size_t)u * HW + (size_t)t * WOUT]                   \
                  : 0.0f;                                                     \
    }                                                                         \
    DOT_CORE(BF)                                                              \
  }

  // steady compute: KY-1 <= R <= FF-1, all taps valid, uniform-base vv loads
#define COMPUTE_S(R, BF)                                                      \
  {                                                                           \
    float vv[KY];                                                             \
    vv[0] = vbase0[(size_t)((R)-0) * HW + lane];                              \
    vv[1] = vbase1[(size_t)((R)-1) * HW + lane];                              \
    vv[2] = vbase2[(size_t)((R)-2) * HW + lane];                              \
    vv[3] = vbase3[(size_t)((R)-3) * HW + lane];                              \
    DOT_CORE(BF)                                                              \
  }

  if constexpr (DMA) {
    STAGE_DMA(0, 0);
    // prologue: r = 0,1,2 (guarded)
    STAGE_DMA(1, 1);
    COMPUTE_G(0, 0);
    LDS_FENCE();        // reads of buf0 drained before overwrite
    STAGE_DMA(2, 0);
    COMPUTE_G(1, 1);
    LDS_FENCE();
    STAGE_DMA(3, 1);
    COMPUTE_G(2, 0);
    // steady: r = 3..50, no guards, uniform vv bases
#pragma unroll 1
    for (int r = 3; r < FF; r += 2) {
      LDS_FENCE();
      STAGE_DMA(r + 1, 0);
      COMPUTE_S(r, 1);
      LDS_FENCE();
      STAGE_DMA(r + 2, 1);
      COMPUTE_S(r + 1, 0);
    }
    // epilogue: r = 51,52,53 (guarded)
    LDS_FENCE();
    STAGE_DMA(52, 0);
    COMPUTE_G(51, 1);
    LDS_FENCE();
    STAGE_DMA(53, 1);
    COMPUTE_G(52, 0);
    COMPUTE_G(53, 1);
  } else {
    STAGE_LOAD(0);
    STAGE_WRITE(0);
#pragma unroll 1
    for (int r = 0; r < NSTEP; r += 2) {
      STAGE_LOAD(r + 1);
      COMPUTE_G(r, 0);
      STAGE_WRITE(1);
      const bool more = (r + 2 < NSTEP);
      if (more) { STAGE_LOAD(r + 2); }
      COMPUTE_G(r + 1, 1);
      if (more) { STAGE_WRITE(0); }
    }
  }

  // ---- cross-wave fx reduction (4-way), then store
  if (w > 0) {
#pragma unroll
    for (int c = 0; c < CC; ++c)
#pragma unroll
      for (int t = 0; t < KY; ++t) sRed[w - 1][c][t][lane] = acc[c][t];
  }
  __syncthreads();
  if (w == 0) {
    float* outb = Out + (size_t)b * CC * HW + (size_t)y0 * WOUT + x0 + lane;
#pragma unroll
    for (int c = 0; c < CC; ++c)
#pragma unroll
      for (int t = 0; t < KY; ++t)
        outb[(size_t)c * HW + (size_t)t * WOUT] =
            acc[c][t] + sRed[0][c][t][lane] + sRed[1][c][t][lane] +
            sRed[2][c][t][lane];
  }
#undef STAGE_LOAD
#undef STAGE_WRITE
#undef STAGE_DMA
#undef DOT_CORE
#undef COMPUTE_G
#undef COMPUTE_S
}

extern "C" void kernel_launch(void* const* d_in, const int* in_sizes, int n_in,
                              void* d_out, int out_size, void* d_ws, size_t ws_size,
                              hipStream_t stream) {
  const float* In = (const float*)d_in[0];
  const float* Ver = (const float*)d_in[1];
  const float* Hor = (const float*)d_in[2];
  float* Out = (float*)d_out;

  dim3 grid(WOUT / LANES, HOUT / KY, BB);
  dim3 block(LANES, NW, 1);

  if (ws_size >= IN16_BYTES && d_ws != nullptr) {
    const int n2 = (int)(BB * CC * HIN * WIN / 2);  // exact (even count)
    cvt16_kernel<<<2048, 256, 0, stream>>>(In, (unsigned int*)d_ws, n2);
    sepconv_kernel<true><<<grid, block, 0, stream>>>(
        In, Ver, Hor, Out, (const unsigned short*)d_ws);
  } else {
    sepconv_kernel<false><<<grid, block, 0, stream>>>(In, Ver, Hor, Out,
                                                      nullptr);
  }
}